// Round 7
// baseline (86.816 us; speedup 1.0000x reference)
//
#include <hip/hip_runtime.h>
#include <math.h>

#define D_ 10
#define N_ 500
#define REC 164   // packed per-(d,n) weight record, floats

typedef float f32x2 __attribute__((ext_vector_type(2)));

__device__ __forceinline__ float fexp2(float x){ float r; asm("v_exp_f32 %0, %1" : "=v"(r) : "v"(x)); return r; }
__device__ __forceinline__ float flog2(float x){ float r; asm("v_log_f32 %0, %1" : "=v"(r) : "v"(x)); return r; }
__device__ __forceinline__ float frcp (float x){ float r; asm("v_rcp_f32 %0, %1" : "=v"(r) : "v"(x)); return r; }

#define LOG2E 1.4426950408889634f
#define LN2   0.6931471805599453f

__device__ __forceinline__ float fast_tanh(float x){
  float e = fexp2(x * (2.0f*LOG2E));
  return 1.0f - 2.0f*frcp(e + 1.0f);
}
__device__ __forceinline__ float softplus10(float x){
  float e = fexp2(x * (10.0f*LOG2E));
  return (0.1f*LN2) * flog2(1.0f + e);
}

// ---- packed-f32 primitives (VOP3P). Weight operand now a VGPR pair
// (same value in all lanes, loaded via global_load -> deep vmcnt queue);
// op_sel/op_sel_hi broadcast the chosen word to both result halves.
__device__ __forceinline__ f32x2 pk_fma_blo(f32x2 a, f32x2 w, f32x2 c){
  f32x2 d; asm("v_pk_fma_f32 %0, %1, %2, %3 op_sel:[0,0,0] op_sel_hi:[1,0,1]"
               : "=v"(d) : "v"(a), "v"(w), "v"(c)); return d; }
__device__ __forceinline__ f32x2 pk_fma_bhi(f32x2 a, f32x2 w, f32x2 c){
  f32x2 d; asm("v_pk_fma_f32 %0, %1, %2, %3 op_sel:[0,1,0] op_sel_hi:[1,1,1]"
               : "=v"(d) : "v"(a), "v"(w), "v"(c)); return d; }
__device__ __forceinline__ f32x2 pk_mul_blo(f32x2 a, f32x2 w){
  f32x2 d; asm("v_pk_mul_f32 %0, %1, %2 op_sel:[0,0] op_sel_hi:[1,0]"
               : "=v"(d) : "v"(a), "v"(w)); return d; }
__device__ __forceinline__ f32x2 pk_mul_bhi(f32x2 a, f32x2 w){
  f32x2 d; asm("v_pk_mul_f32 %0, %1, %2 op_sel:[0,1] op_sel_hi:[1,1]"
               : "=v"(d) : "v"(a), "v"(w)); return d; }
__device__ __forceinline__ f32x2 pk_mul(f32x2 a, f32x2 b){
  f32x2 d; asm("v_pk_mul_f32 %0, %1, %2" : "=v"(d) : "v"(a), "v"(b)); return d; }
__device__ __forceinline__ f32x2 pk_add(f32x2 a, f32x2 b){
  f32x2 d; asm("v_pk_add_f32 %0, %1, %2" : "=v"(d) : "v"(a), "v"(b)); return d; }
__device__ __forceinline__ f32x2 pk_nfma(f32x2 a, f32x2 b, f32x2 c){ // c - a*b
  f32x2 d; asm("v_pk_fma_f32 %0, %1, %2, %3 neg_lo:[1,0,0] neg_hi:[1,0,0]"
               : "=v"(d) : "v"(a), "v"(b), "v"(c)); return d; }

#define LD2(off)        (*(const f32x2*)(r + ((off) & ~1)))
#define FMA_B(a, off, c) (((off)&1) ? pk_fma_bhi((a), LD2(off), (c)) : pk_fma_blo((a), LD2(off), (c)))
#define MUL_B(a, off)    (((off)&1) ? pk_mul_bhi((a), LD2(off))      : pk_mul_blo((a), LD2(off)))

// exp-based packed tanh + derivative with paired rcp:
// 2 exp + 1 rcp + 7 VALU per f32x2 activation pair.
__device__ __forceinline__ void act_tanh(f32x2 pre, f32x2 ONE, f32x2 TWO, f32x2 K2,
                                         f32x2* th, f32x2* td){
  f32x2 tt = pk_mul(pre, K2);
  f32x2 e; e.x = fexp2(tt.x); e.y = fexp2(tt.y);
  f32x2 p1 = pk_add(e, ONE);
  float pr = p1.x * p1.y;
  float rr = frcp(pr);
  f32x2 rc; rc.x = p1.y * rr; rc.y = p1.x * rr;
  f32x2 t = pk_nfma(TWO, rc, ONE);
  *th = t;
  *td = pk_nfma(t, t, ONE);   // 1 - tanh^2
}

// Record layout (161 used, padded to 164):
//   [0..4] W0   [5..9] bs0   [10..14] ta0
//   mid l=0..3 at base 15+l*35: [base+j*5+k]=W^T, [base+25+j]=bs, [base+30+j]=ta
//   [155..159] Wl   [160] b_last
__global__ __launch_bounds__(256) void tennet_prep(
    const float* __restrict__ w_first, const float* __restrict__ w_mid,
    const float* __restrict__ w_last, const float* __restrict__ bs,
    const float* __restrict__ b_last, const float* __restrict__ a_all,
    float* __restrict__ rec)
{
  int rid = blockIdx.x*4 + (threadIdx.x >> 6);
  int lane = threadIdx.x & 63;
  int d = rid / N_;
  int n = rid - d*N_;
  float* dst = rec + rid*REC;
  for (int i = lane; i < 161; i += 64) {
    float v;
    if (i < 5)        v = softplus10(w_first[(d*N_+n)*5 + i]);
    else if (i < 10)  v = bs[(d*N_+n)*5 + (i-5)];
    else if (i < 15)  v = fast_tanh(a_all[(d*N_+n)*5 + (i-10)]);
    else if (i < 155) {
      int q = i - 15; int l = q/35; int r2 = q - l*35;
      if (r2 < 25) {
        int j = r2/5, k = r2 - (r2/5)*5;
        v = softplus10(w_mid[((l*D_+d)*N_+n)*25 + k*5 + j]);
      } else if (r2 < 30) {
        v = bs[(((l+1)*D_+d)*N_+n)*5 + (r2-25)];
      } else {
        v = fast_tanh(a_all[(((l+1)*D_+d)*N_+n)*5 + (r2-30)]);
      }
    }
    else if (i < 160) v = softplus10(w_last[(d*N_+n)*5 + (i-155)]);
    else              v = b_last[d*N_+n];
    dst[i] = v;
  }
}

// One wave per (d,n); 64 lanes x 2 m per thread (m and m+64), packed f32 math.
// Weights fetched via VMEM (divergent-typed wave id -> global_load_dwordx2,
// one L1 line per load, deep vmcnt pipelining). launch_bounds(512,8) pins
// VGPR<=64 so 8 waves/SIMD stay resident.
__global__ __launch_bounds__(512, 8) void tennet_main(
    const float* __restrict__ X, const float* __restrict__ rec,
    float* __restrict__ out0)
{
  __shared__ float tr[128*9];
  int bid = blockIdx.x;
  int mb  = bid & 7;            // 8 chunks of 128 m
  int q   = bid >> 3;
  int d   = q / 63;             // 10
  int nch = q - d*63;           // 63 chunks of 8 n (covers 504 >= 500)
  int n0 = nch*8;
  int t = threadIdx.x;
  int wv = t >> 6;              // NOT readfirstlane'd: keep divergent-typed -> VMEM
  int lane = t & 63;
  int n = n0 + wv;
  int nr = (n < N_) ? n : (N_-1);
  const float* r = rec + (d*N_ + nr)*REC;
  int m0 = mb*128 + lane;

  f32x2 x;
  x.x = X[m0*D_ + d];
  x.y = X[(m0+64)*D_ + d];

  const f32x2 ONE = {1.0f, 1.0f};
  const f32x2 TWO = {2.0f, 2.0f};
  const f32x2 K2  = {2.0f*LOG2E, 2.0f*LOG2E};
  const f32x2 NL2E = {-LOG2E, -LOG2E};

  f32x2 phis[5], phid[5];
  // layer 0 (k-dim = 1)
  #pragma unroll
  for (int j = 0; j < 5; ++j) {
    f32x2 pre = FMA_B(x, j, MUL_B(ONE, 5+j));     // x*w0 + b
    f32x2 th, td;
    act_tanh(pre, ONE, TWO, K2, &th, &td);
    f32x2 uf = FMA_B(td, 10+j, ONE);              // 1 + ta*td
    phid[j] = MUL_B(uf, j);                       // w0 * uf
    phis[j] = FMA_B(th, 10+j, pre);               // pre + th*ta
  }
  // mid layers
  #pragma unroll
  for (int l = 0; l < 4; ++l) {
    const int base = 15 + l*35;
    f32x2 nphis[5], nphid[5];
    #pragma unroll
    for (int j = 0; j < 5; ++j) {
      f32x2 pre = FMA_B(phis[0], base + j*5, MUL_B(ONE, base + 25 + j));
      f32x2 pd  = MUL_B(phid[0], base + j*5);
      #pragma unroll
      for (int k = 1; k < 5; ++k) {
        pre = FMA_B(phis[k], base + j*5 + k, pre);
        pd  = FMA_B(phid[k], base + j*5 + k, pd);
      }
      f32x2 th, td;
      act_tanh(pre, ONE, TWO, K2, &th, &td);
      f32x2 uf = FMA_B(td, base + 30 + j, ONE);
      nphid[j] = pk_mul(pd, uf);
      nphis[j] = FMA_B(th, base + 30 + j, pre);
    }
    #pragma unroll
    for (int j = 0; j < 5; ++j){ phis[j]=nphis[j]; phid[j]=nphid[j]; }
  }
  // last layer + sigmoid' (paired rcp)
  f32x2 pre = FMA_B(phis[0], 155, MUL_B(ONE, 160));
  f32x2 pd  = MUL_B(phid[0], 155);
  #pragma unroll
  for (int k = 1; k < 5; ++k) {
    pre = FMA_B(phis[k], 155 + k, pre);
    pd  = FMA_B(phid[k], 155 + k, pd);
  }
  f32x2 tt = pk_mul(pre, NL2E);
  f32x2 e; e.x = fexp2(tt.x); e.y = fexp2(tt.y);
  f32x2 p1 = pk_add(e, ONE);
  float prd = p1.x * p1.y;
  float rrc = frcp(prd);
  f32x2 sg; sg.x = p1.y * rrc; sg.y = p1.x * rrc;
  f32x2 om = pk_nfma(sg, ONE, ONE);               // 1 - sg
  f32x2 res = pk_mul(pk_mul(pd, sg), om);

  // transpose 128m x 8n through LDS (stride 9 -> <=2-way banks, free)
  tr[lane*9 + wv]      = res.x;
  tr[(lane+64)*9 + wv] = res.y;
  __syncthreads();
  int tn = t & 7;
  #pragma unroll
  for (int p = 0; p < 2; ++p) {
    int rr2 = (t >> 3) + p*64;
    if (n0 + tn < N_)
      out0[((mb*128 + rr2)*D_ + d)*N_ + n0 + tn] = tr[rr2*9 + tn];
  }
}

// fm[m] = min_n mean_d( -ln(phidot[m,d,n] + 1e-10) )
__global__ __launch_bounds__(512) void tennet_fm(
    const float* __restrict__ out0, float* __restrict__ fm)
{
  int m = blockIdx.x;
  int t = threadIdx.x;
  float val = INFINITY;
  if (t < N_) {
    float acc = 0.0f;
    #pragma unroll
    for (int d = 0; d < D_; ++d) {
      float v = out0[(m*D_ + d)*N_ + t];
      acc += flog2(v + 1e-10f);
    }
    val = -acc * (LN2 / (float)D_);
  }
  #pragma unroll
  for (int off = 32; off; off >>= 1) {
    float o = __shfl_down(val, off, 64);
    val = fminf(val, o);
  }
  __shared__ float red[8];
  int wid = t >> 6;
  if ((t & 63) == 0) red[wid] = val;
  __syncthreads();
  if (t == 0) {
    float v = red[0];
    #pragma unroll
    for (int ww = 1; ww < 8; ++ww) v = fminf(v, red[ww]);
    fm[m] = v;
  }
}

extern "C" void kernel_launch(void* const* d_in, const int* in_sizes, int n_in,
                              void* d_out, int out_size, void* d_ws, size_t ws_size,
                              hipStream_t stream) {
  const float* X       = (const float*)d_in[0];
  const float* w_first = (const float*)d_in[1];
  const float* w_mid   = (const float*)d_in[2];
  const float* w_last  = (const float*)d_in[3];
  const float* bs      = (const float*)d_in[4];
  const float* b_last  = (const float*)d_in[5];
  const float* a_all   = (const float*)d_in[6];
  float* out0 = (float*)d_out;
  float* fm   = out0 + 1024*D_*N_;
  float* rec  = (float*)d_ws;   // 10*500*164*4 = 3.28 MB

  tennet_prep<<<(D_*N_)/4, 256, 0, stream>>>(w_first, w_mid, w_last, bs, b_last, a_all, rec);
  tennet_main<<<10*63*8, 512, 0, stream>>>(X, rec, out0);
  tennet_fm<<<1024, 512, 0, stream>>>(out0, fm);
}

// Round 8
// 66.046 us; speedup vs baseline: 1.3145x; 1.3145x over previous
//
#include <hip/hip_runtime.h>
#include <math.h>

#define D_ 10
#define N_ 500
#define REC 164   // packed per-(d,n) weight record, floats

typedef float f32x2 __attribute__((ext_vector_type(2)));

// Compiler intrinsics (no asm boundaries -> no marshaling movs, free scheduling)
__device__ __forceinline__ float fexp2(float x){ return __builtin_amdgcn_exp2f(x); }
__device__ __forceinline__ float flog2(float x){ return __builtin_amdgcn_logf(x); }
__device__ __forceinline__ float frcp (float x){ return __builtin_amdgcn_rcpf(x); }

#define LOG2E 1.4426950408889634f
#define LN2   0.6931471805599453f

__device__ __forceinline__ float fast_tanh(float x){
  float e = fexp2(x * (2.0f*LOG2E));
  return 1.0f - 2.0f*frcp(e + 1.0f);
}
__device__ __forceinline__ float softplus10(float x){
  float e = fexp2(x * (10.0f*LOG2E));
  return (0.1f*LN2) * flog2(1.0f + e);
}

// exp-based packed tanh + derivative with paired rcp, plain C++ on float2:
// 2 exp + 1 rcp + a handful of (hopefully pk-) VALU ops.
__device__ __forceinline__ void act_tanh(f32x2 pre, f32x2* th, f32x2* td){
  f32x2 e;
  e.x = fexp2(pre.x * (2.0f*LOG2E));
  e.y = fexp2(pre.y * (2.0f*LOG2E));
  f32x2 p1 = e + 1.0f;
  float pr = p1.x * p1.y;
  float rr = frcp(pr);
  f32x2 rc;
  rc.x = p1.y * rr;
  rc.y = p1.x * rr;
  f32x2 t = 1.0f - 2.0f*rc;
  *th = t;
  *td = 1.0f - t*t;
}

// Record layout (161 used, padded to 164):
//   [0..4] W0   [5..9] bs0   [10..14] ta0
//   mid l=0..3 at base 15+l*35: [base+j*5+k]=W^T, [base+25+j]=bs, [base+30+j]=ta
//   [155..159] Wl   [160] b_last
__global__ __launch_bounds__(256) void tennet_prep(
    const float* __restrict__ w_first, const float* __restrict__ w_mid,
    const float* __restrict__ w_last, const float* __restrict__ bs,
    const float* __restrict__ b_last, const float* __restrict__ a_all,
    float* __restrict__ rec)
{
  int rid = blockIdx.x*4 + (threadIdx.x >> 6);
  int lane = threadIdx.x & 63;
  int d = rid / N_;
  int n = rid - d*N_;
  float* dst = rec + rid*REC;
  for (int i = lane; i < 161; i += 64) {
    float v;
    if (i < 5)        v = softplus10(w_first[(d*N_+n)*5 + i]);
    else if (i < 10)  v = bs[(d*N_+n)*5 + (i-5)];
    else if (i < 15)  v = fast_tanh(a_all[(d*N_+n)*5 + (i-10)]);
    else if (i < 155) {
      int q = i - 15; int l = q/35; int r2 = q - l*35;
      if (r2 < 25) {
        int j = r2/5, k = r2 - (r2/5)*5;
        v = softplus10(w_mid[((l*D_+d)*N_+n)*25 + k*5 + j]);
      } else if (r2 < 30) {
        v = bs[(((l+1)*D_+d)*N_+n)*5 + (r2-25)];
      } else {
        v = fast_tanh(a_all[(((l+1)*D_+d)*N_+n)*5 + (r2-30)]);
      }
    }
    else if (i < 160) v = softplus10(w_last[(d*N_+n)*5 + (i-155)]);
    else              v = b_last[d*N_+n];
    dst[i] = v;
  }
}

// One wave per (d,n); 64 lanes x 2 m per thread (m and m+64).
// Plain C++ float2 math; weights wave-uniform (readfirstlane -> s_load),
// scalar weight values broadcast into packed ops by the compiler.
__global__ __launch_bounds__(512) void tennet_main(
    const float* __restrict__ X, const float* __restrict__ rec,
    float* __restrict__ out0)
{
  __shared__ float tr[128*9];
  int bid = blockIdx.x;
  int mb  = bid & 7;            // 8 chunks of 128 m
  int q   = bid >> 3;
  int d   = q / 63;             // 10
  int nch = q - d*63;           // 63 chunks of 8 n (covers 504 >= 500)
  int n0 = nch*8;
  int t = threadIdx.x;
  int wv = __builtin_amdgcn_readfirstlane(t >> 6);   // uniform wave id -> s_load
  int lane = t & 63;
  int n = n0 + wv;
  int nr = (n < N_) ? n : (N_-1);
  const float* r = rec + (d*N_ + nr)*REC;
  int m0 = mb*128 + lane;

  f32x2 x;
  x.x = X[m0*D_ + d];
  x.y = X[(m0+64)*D_ + d];

  f32x2 phis[5], phid[5];
  // layer 0 (k-dim = 1)
  #pragma unroll
  for (int j = 0; j < 5; ++j) {
    f32x2 pre = x * r[j] + r[5+j];
    f32x2 th, td;
    act_tanh(pre, &th, &td);
    phid[j] = (1.0f + r[10+j]*td) * r[j];
    phis[j] = pre + th * r[10+j];
  }
  // mid layers
  #pragma unroll
  for (int l = 0; l < 4; ++l) {
    const int base = 15 + l*35;
    f32x2 nphis[5], nphid[5];
    #pragma unroll
    for (int j = 0; j < 5; ++j) {
      f32x2 pre = phis[0] * r[base + j*5] + r[base + 25 + j];
      f32x2 pd  = phid[0] * r[base + j*5];
      #pragma unroll
      for (int k = 1; k < 5; ++k) {
        pre += phis[k] * r[base + j*5 + k];
        pd  += phid[k] * r[base + j*5 + k];
      }
      f32x2 th, td;
      act_tanh(pre, &th, &td);
      nphid[j] = pd * (1.0f + r[base + 30 + j]*td);
      nphis[j] = pre + th * r[base + 30 + j];
    }
    #pragma unroll
    for (int j = 0; j < 5; ++j){ phis[j]=nphis[j]; phid[j]=nphid[j]; }
  }
  // last layer + sigmoid' (paired rcp)
  f32x2 pre = phis[0] * r[155] + r[160];
  f32x2 pd  = phid[0] * r[155];
  #pragma unroll
  for (int k = 1; k < 5; ++k) {
    pre += phis[k] * r[155 + k];
    pd  += phid[k] * r[155 + k];
  }
  f32x2 e;
  e.x = fexp2(pre.x * (-LOG2E));
  e.y = fexp2(pre.y * (-LOG2E));
  f32x2 p1 = e + 1.0f;
  float prd = p1.x * p1.y;
  float rrc = frcp(prd);
  f32x2 sg;
  sg.x = p1.y * rrc;
  sg.y = p1.x * rrc;
  f32x2 res = pd * sg * (1.0f - sg);

  // transpose 128m x 8n through LDS (stride 9 -> <=2-way banks, free)
  tr[lane*9 + wv]      = res.x;
  tr[(lane+64)*9 + wv] = res.y;
  __syncthreads();
  int tn = t & 7;
  #pragma unroll
  for (int p = 0; p < 2; ++p) {
    int rr2 = (t >> 3) + p*64;
    if (n0 + tn < N_)
      out0[((mb*128 + rr2)*D_ + d)*N_ + n0 + tn] = tr[rr2*9 + tn];
  }
}

// fm[m] = min_n mean_d( -ln(phidot[m,d,n] + 1e-10) )
__global__ __launch_bounds__(512) void tennet_fm(
    const float* __restrict__ out0, float* __restrict__ fm)
{
  int m = blockIdx.x;
  int t = threadIdx.x;
  float val = INFINITY;
  if (t < N_) {
    float acc = 0.0f;
    #pragma unroll
    for (int d = 0; d < D_; ++d) {
      float v = out0[(m*D_ + d)*N_ + t];
      acc += flog2(v + 1e-10f);
    }
    val = -acc * (LN2 / (float)D_);
  }
  #pragma unroll
  for (int off = 32; off; off >>= 1) {
    float o = __shfl_down(val, off, 64);
    val = fminf(val, o);
  }
  __shared__ float red[8];
  int wid = t >> 6;
  if ((t & 63) == 0) red[wid] = val;
  __syncthreads();
  if (t == 0) {
    float v = red[0];
    #pragma unroll
    for (int ww = 1; ww < 8; ++ww) v = fminf(v, red[ww]);
    fm[m] = v;
  }
}

extern "C" void kernel_launch(void* const* d_in, const int* in_sizes, int n_in,
                              void* d_out, int out_size, void* d_ws, size_t ws_size,
                              hipStream_t stream) {
  const float* X       = (const float*)d_in[0];
  const float* w_first = (const float*)d_in[1];
  const float* w_mid   = (const float*)d_in[2];
  const float* w_last  = (const float*)d_in[3];
  const float* bs      = (const float*)d_in[4];
  const float* b_last  = (const float*)d_in[5];
  const float* a_all   = (const float*)d_in[6];
  float* out0 = (float*)d_out;
  float* fm   = out0 + 1024*D_*N_;
  float* rec  = (float*)d_ws;   // 10*500*164*4 = 3.28 MB

  tennet_prep<<<(D_*N_)/4, 256, 0, stream>>>(w_first, w_mid, w_last, bs, b_last, a_all, rec);
  tennet_main<<<10*63*8, 512, 0, stream>>>(X, rec, out0);
  tennet_fm<<<1024, 512, 0, stream>>>(out0, fm);
}